// Round 4
// baseline (1430.696 us; speedup 1.0000x reference)
//
#include <hip/hip_runtime.h>

// Problem constants: B=4, C=64 (in & out for deform), H=W=256.
#define BB 4
#define CC 64
#define HH 256
#define WW 256
#define HWHW 65536

typedef __bf16 bf16x8 __attribute__((ext_vector_type(8)));
typedef float f32x16 __attribute__((ext_vector_type(16)));

__device__ __forceinline__ unsigned short f32_to_bf16(float s) {
    unsigned int xi = __builtin_bit_cast(unsigned int, s);
    unsigned int r = (xi + 0x7fffu + ((xi >> 16) & 1u)) >> 16;  // RNE
    return (unsigned short)r;
}
__device__ __forceinline__ unsigned pack2bf(float a, float b) {
    return (unsigned)f32_to_bf16(a) | ((unsigned)f32_to_bf16(b) << 16);
}
__device__ __forceinline__ float bf_lo(unsigned u) { return __builtin_bit_cast(float, u << 16); }
__device__ __forceinline__ float bf_hi(unsigned u) { return __builtin_bit_cast(float, u & 0xffff0000u); }

// ---------------------------------------------------------------------------
// Weight prep. Both GEMMs use K-order k = chunk*144 + stage*72 + tap*8 + (c&7)
// with c = chunk*16 + stage*8 + (c&7). Layout [kslot][n(64)][j(8)] bf16.
//   WB: deform weights dc_w[n][c][tap]           (36864 bf16)
//   WA: offset weights, n<18 real, n>=18 zero    (36864 bf16)
// ---------------------------------------------------------------------------
__global__ void prep_weights(const float* __restrict__ offset_w,
                             const float* __restrict__ dc_w,
                             unsigned short* __restrict__ WB,
                             unsigned short* __restrict__ WA) {
    int j = blockIdx.x * 256 + threadIdx.x;
    if (j < 36864) {
        int kslot = j >> 9, n = (j >> 3) & 63, jj = j & 7;
        int chunk = kslot / 18, r = kslot - chunk * 18;
        int s2 = r / 9, tap = r - s2 * 9;
        int c = chunk * 16 + s2 * 8 + jj;
        WB[j] = f32_to_bf16(dc_w[(n * CC + c) * 9 + tap]);
    }
    int j2 = j - 36864;
    if (j2 >= 0 && j2 < 36864) {
        int kslot = j2 >> 9, n = (j2 >> 3) & 63, jj = j2 & 7;
        int chunk = kslot / 18, r = kslot - chunk * 18;
        int s2 = r / 9, tap = r - s2 * 9;
        int c = chunk * 16 + s2 * 8 + jj;
        WA[j2] = (n < 18) ? f32_to_bf16(offset_w[(n * CC + c) * 9 + tap])
                          : (unsigned short)0;
    }
}

// ---------------------------------------------------------------------------
// Stage an 8-channel, 9-row x 72-col fp32 window [y-4..y+4] x [xbase-4..xbase+67]
// into LDS with coalesced float2 loads (clamped replication at borders).
// win layout: [ch][row][col], col-stride 72 dwords, ch-stride 648 dwords.
// ---------------------------------------------------------------------------
__device__ __forceinline__ void stage_window(const float* __restrict__ img,
                                             float* __restrict__ win,
                                             int cbase, int y, int xbase, int t) {
#pragma unroll
    for (int it = 0; it < 11; ++it) {
        int j2 = t + it * 256;
        if (j2 < 2592) {
            int ch = j2 / 324;
            int rem = j2 - ch * 324;
            int r = rem / 36;
            int c2 = rem - r * 36;
            int gy = min(max(y - 4 + r, 0), HH - 1);
            int gx0 = xbase - 4 + 2 * c2;
            const float* src = img + (size_t)(cbase + ch) * HWHW + gy * WW;
            float va, vb;
            if (gx0 >= 0 && gx0 + 1 < WW) {
                const float2 v = *(const float2*)(src + gx0);
                va = v.x; vb = v.y;
            } else {
                va = src[min(max(gx0, 0), WW - 1)];
                vb = src[min(max(gx0 + 1, 0), WW - 1)];
            }
            *(float2*)(win + ch * 648 + r * 72 + 2 * c2) = make_float2(va, vb);
        }
    }
}

// ---------------------------------------------------------------------------
// Offset conv as implicit MFMA GEMM (M=262144, N=64 padded from 18, K=576).
// Taps read from the LDS window (always in-window), zero-padding via masks.
// ---------------------------------------------------------------------------
__global__ __launch_bounds__(256, 4) void offset_mfma(
    const float* __restrict__ blur, const unsigned short* __restrict__ WA,
    const float* __restrict__ ob, float* __restrict__ offout) {
    __shared__ __align__(16) float ldsf[9792];           // win 5184 + S 4608 dwords
    float* win = ldsf;
    unsigned int* Sd = (unsigned int*)(ldsf + 5184);

    const int t = threadIdx.x;
    const int px = t & 63;
    const int cg = t >> 6;
    const int blk = blockIdx.x;
    const int xseg = blk & 3;
    const int y = (blk >> 2) & (HH - 1);
    const int b = blk >> 10;
    const int xbase = xseg * 64;
    const int x = xbase + px;

    const float* img = blur + (size_t)b * CC * HWHW;

    // window coords (always valid) + zero-pad masks
    int rw[3], cw[3];
    float m[9];
#pragma unroll
    for (int dy = 0; dy < 3; ++dy) {
        int yy = y + dy - 1;
        rw[dy] = (min(max(yy, 0), HH - 1) - (y - 4)) * 72;
        bool vy = (yy >= 0) && (yy < HH);
#pragma unroll
        for (int dx = 0; dx < 3; ++dx) {
            int xx = x + dx - 1;
            m[dy * 3 + dx] = (vy && xx >= 0 && xx < WW) ? 1.0f : 0.0f;
        }
    }
#pragma unroll
    for (int dx = 0; dx < 3; ++dx)
        cw[dx] = min(max(x + dx - 1, 0), WW - 1) - (xbase - 4);

    f32x16 acc = {0, 0, 0, 0, 0, 0, 0, 0, 0, 0, 0, 0, 0, 0, 0, 0};
    const int half = px >> 5;
    const int l31 = px & 31;
    const int px_i = ((cg >> 1) * 32) + l31;
    const int n_i = ((cg & 1) * 32) + l31;

    for (int chunk = 0; chunk < 4; ++chunk) {
#pragma unroll
        for (int s = 0; s < 2; ++s) {
            if (s == 1) __syncthreads();
            stage_window(img, win, chunk * 16 + s * 8, y, xbase, t);
            __syncthreads();
            const float* w0 = win + (cg * 2) * 648;
            const float* w1 = w0 + 648;
#pragma unroll
            for (int k = 0; k < 9; ++k) {
                const int ky = k / 3, kx = k - (k / 3) * 3;
                const int idx = rw[ky] + cw[kx];
                const float sA = w0[idx] * m[k];
                const float sB = w1[idx] * m[k];
                Sd[(((s * 9 + k) * 64 + px) << 2) + cg] = pack2bf(sA, sB);
            }
        }
        __syncthreads();
        const bf16x8* sampV = (const bf16x8*)Sd;
        const unsigned short* wb = WA + (size_t)chunk * 9216;
#pragma unroll
        for (int ks = 0; ks < 9; ++ks) {
            bf16x8 fa = sampV[(ks * 2 + half) * 64 + px_i];
            bf16x8 fb = *(const bf16x8*)(wb + ((size_t)((ks * 2 + half) * 64 + n_i)) * 8);
            acc = __builtin_amdgcn_mfma_f32_32x32x16_bf16(fa, fb, acc, 0, 0, 0);
        }
    }

    // epilogue: transpose (stride 65) -> coalesced stores of n<18 + bias
    {
        const int n_l = (cg & 1) * 32 + l31;
        const int px_b = (cg >> 1) * 32 + 4 * half;
#pragma unroll
        for (int r = 0; r < 16; ++r) {
            const int row = px_b + (r & 3) + 8 * (r >> 2);
            ldsf[n_l * 65 + row] = acc[r];
        }
    }
    __syncthreads();
    {
        float* base = offout + ((size_t)b * 18) * HWHW + y * WW + xbase;
        for (int i = t; i < 18 * 64; i += 256) {
            const int n = i >> 6;
            const int p = i & 63;
            base[(size_t)n * HWHW + p] = ldsf[n * 65 + p] + ob[n];
        }
    }
}

// ---------------------------------------------------------------------------
// Deformable conv as implicit MFMA GEMM with LDS-windowed bilinear gather.
// Fixed LDS offsets {0,+1,+72,+73} via validity-aware base selection; rare
// out-of-window taps fall back to exact global gather (correct for any data).
// ---------------------------------------------------------------------------
__global__ __launch_bounds__(256, 4) void deform_mfma(
    const float* __restrict__ content, const float* __restrict__ offs,
    const unsigned short* __restrict__ WB, const float* __restrict__ bias,
    float* __restrict__ out) {
    __shared__ __align__(16) float ldsf[9792];
    float* win = ldsf;
    unsigned int* Sd = (unsigned int*)(ldsf + 5184);

    const int t = threadIdx.x;
    const int px = t & 63;
    const int cg = t >> 6;
    const int blk = blockIdx.x;
    const int xseg = blk & 3;
    const int y = (blk >> 2) & (HH - 1);
    const int b = blk >> 10;
    const int xbase = xseg * 64;
    const int x = xbase + px;

    const float* img = content + (size_t)b * CC * HWHW;
    const float* offp = offs + ((size_t)b * 18) * HWHW + y * WW + x;

    // per-tap state: packed window index + oow flag; bf16-packed corner weights
    unsigned st[9], wp0[9], wp1[9];
#pragma unroll
    for (int k = 0; k < 9; ++k) {
        const int ky = k / 3, kx = k - (k / 3) * 3;
        const float offy = offp[(size_t)(2 * k) * HWHW];
        const float offx = offp[(size_t)(2 * k + 1) * HWHW];
        const float py = (float)(y + ky - 1) + offy;
        const float pxf = (float)(x + kx - 1) + offx;
        const float y0f = floorf(py), x0f = floorf(pxf);
        const float wy = py - y0f, wxx = pxf - x0f;
        const int y0 = (int)y0f, x0 = (int)x0f;
        const bool vy0 = (y0 >= 0) && (y0 < HH);
        const bool vy1 = (y0 + 1 >= 0) && (y0 + 1 < HH);
        const bool vx0 = (x0 >= 0) && (x0 < WW);
        const bool vx1 = (x0 + 1 >= 0) && (x0 + 1 < WW);
        const float a00 = (vy0 && vx0) ? (1.0f - wy) * (1.0f - wxx) : 0.0f;
        const float a01 = (vy0 && vx1) ? (1.0f - wy) * wxx : 0.0f;
        const float a10 = (vy1 && vx0) ? wy * (1.0f - wxx) : 0.0f;
        const float a11 = (vy1 && vx1) ? wy * wxx : 0.0f;
        wp0[k] = pack2bf(a00, a01);
        wp1[k] = pack2bf(a10, a11);
        const int y0c = min(max(y0, 0), HH - 1);
        const int y1c = min(max(y0 + 1, 0), HH - 1);
        const int x0c = min(max(x0, 0), WW - 1);
        const int x1c = min(max(x0 + 1, 0), WW - 1);
        int ridx = vy0 ? (y0c - (y - 4)) : (y1c - (y - 4) - 1);
        int cidx = vx0 ? (x0c - (xbase - 4)) : (x1c - (xbase - 4) - 1);
        const unsigned oow =
            (unsigned)((ridx < 0) | (ridx > 7) | (cidx < 0) | (cidx > 70));
        ridx = min(max(ridx, 0), 7);
        cidx = min(max(cidx, 0), 70);
        st[k] = (unsigned)(ridx * 72 + cidx) | (oow << 12);
    }

    f32x16 acc = {0, 0, 0, 0, 0, 0, 0, 0, 0, 0, 0, 0, 0, 0, 0, 0};
    const int half = px >> 5;
    const int l31 = px & 31;
    const int px_i = ((cg >> 1) * 32) + l31;
    const int n_i = ((cg & 1) * 32) + l31;

    for (int chunk = 0; chunk < 4; ++chunk) {
#pragma unroll
        for (int s = 0; s < 2; ++s) {
            if (s == 1) __syncthreads();
            stage_window(img, win, chunk * 16 + s * 8, y, xbase, t);
            __syncthreads();
            const float* w0 = win + (cg * 2) * 648;
            const float* w1 = w0 + 648;
            const int cglob = chunk * 16 + s * 8 + cg * 2;
#pragma unroll
            for (int k = 0; k < 9; ++k) {
                const unsigned u = st[k];
                const float* p0 = w0 + (u & 1023);
                const float* p1 = w1 + (u & 1023);
                const float W00 = bf_lo(wp0[k]), W01 = bf_hi(wp0[k]);
                const float W10 = bf_lo(wp1[k]), W11 = bf_hi(wp1[k]);
                float sA = W00 * p0[0] + W01 * p0[1] + W10 * p0[72] + W11 * p0[73];
                float sB = W00 * p1[0] + W01 * p1[1] + W10 * p1[72] + W11 * p1[73];
                if (u >> 12) {  // cold path: out-of-window -> exact global gather
                    const int ky = k / 3, kx = k - (k / 3) * 3;
                    const float offy = offp[(size_t)(2 * k) * HWHW];
                    const float offx = offp[(size_t)(2 * k + 1) * HWHW];
                    const int y0 = (int)floorf((float)(y + ky - 1) + offy);
                    const int x0 = (int)floorf((float)(x + kx - 1) + offx);
                    const int y0c = min(max(y0, 0), HH - 1);
                    const int y1c = min(max(y0 + 1, 0), HH - 1);
                    const int x0c = min(max(x0, 0), WW - 1);
                    const int x1c = min(max(x0 + 1, 0), WW - 1);
                    const float* plA = img + (size_t)cglob * HWHW;
                    const float* plB = plA + HWHW;
                    sA = W00 * plA[y0c * WW + x0c] + W01 * plA[y0c * WW + x1c] +
                         W10 * plA[y1c * WW + x0c] + W11 * plA[y1c * WW + x1c];
                    sB = W00 * plB[y0c * WW + x0c] + W01 * plB[y0c * WW + x1c] +
                         W10 * plB[y1c * WW + x0c] + W11 * plB[y1c * WW + x1c];
                }
                Sd[(((s * 9 + k) * 64 + px) << 2) + cg] = pack2bf(sA, sB);
            }
        }
        __syncthreads();
        const bf16x8* sampV = (const bf16x8*)Sd;
        const unsigned short* wb = WB + (size_t)chunk * 9216;
#pragma unroll
        for (int ks = 0; ks < 9; ++ks) {
            bf16x8 fa = sampV[(ks * 2 + half) * 64 + px_i];
            bf16x8 fb = *(const bf16x8*)(wb + ((size_t)((ks * 2 + half) * 64 + n_i)) * 8);
            acc = __builtin_amdgcn_mfma_f32_32x32x16_bf16(fa, fb, acc, 0, 0, 0);
        }
    }

    // epilogue: transpose (stride 65) -> coalesced stores + bias
    {
        const int n_l = (cg & 1) * 32 + l31;
        const int px_b = (cg >> 1) * 32 + 4 * half;
#pragma unroll
        for (int r = 0; r < 16; ++r) {
            const int row = px_b + (r & 3) + 8 * (r >> 2);
            ldsf[n_l * 65 + row] = acc[r];
        }
    }
    __syncthreads();
    {
        float* base = out + (size_t)b * CC * HWHW + y * WW + xbase;
        for (int i = t; i < 4096; i += 256) {
            const int n = i >> 6;
            const int p = i & 63;
            base[(size_t)n * HWHW + p] = ldsf[n * 65 + p] + bias[n];
        }
    }
}

// ---------------------------------------------------------------------------
extern "C" void kernel_launch(void* const* d_in, const int* in_sizes, int n_in,
                              void* d_out, int out_size, void* d_ws, size_t ws_size,
                              hipStream_t stream) {
    const float* content  = (const float*)d_in[0];
    const float* blur     = (const float*)d_in[1];
    const float* offset_w = (const float*)d_in[2];
    const float* offset_b = (const float*)d_in[3];
    const float* dc_w     = (const float*)d_in[4];
    const float* dc_b     = (const float*)d_in[5];

    float* out0    = (float*)d_out;                     // (4,64,256,256)
    float* off_out = out0 + (size_t)BB * CC * HWHW;     // (4,18,256,256)

    unsigned short* WB = (unsigned short*)d_ws;         // 36864 bf16
    unsigned short* WA = WB + 36864;                    // 36864 bf16

    prep_weights<<<288, 256, 0, stream>>>(offset_w, dc_w, WB, WA);
    offset_mfma<<<BB * HH * 4, 256, 0, stream>>>(blur, WA, offset_b, off_out);
    deform_mfma<<<BB * HH * 4, 256, 0, stream>>>(content, off_out, WB, dc_b, out0);
}